// Round 1
// 141.724 us; speedup vs baseline: 1.0663x; 1.0663x over previous
//
#include <hip/hip_runtime.h>

#define SEQ 2048
#define HD 64
#define NBH 24
#define ROWB 144   // padded K/V LDS row stride in bytes (72 bf16, proven)

// ---------------- workspace layout (proven rounds 5-8) ----------------
#define MB_OFF   0
#define MB_BYTES (32 * 32 * 512)                 // 512 KB: [qtb][kt][64 q-rows][u64 of k-bits]
#define QB_OFF   (MB_OFF + MB_BYTES)
#define QK_BYTES (NBH * SEQ * HD * 2)            // 6 MB bf16, plain 128B rows
#define KB_OFF   (QB_OFF + QK_BYTES)
#define VT_OFF   (KB_OFF + QK_BYTES)             // V^T pre-tiled: [bh][kt] 8KB tiles, d-major 128B rows
#define WS_NEED  ((size_t)(VT_OFF + QK_BYTES))   // ~18.5 MB

typedef __bf16 bfrag8 __attribute__((ext_vector_type(8)));
typedef __bf16 bf16x4 __attribute__((ext_vector_type(4)));
typedef float  floatx4 __attribute__((ext_vector_type(4)));
typedef float  floatx16 __attribute__((ext_vector_type(16)));

__device__ __forceinline__ floatx4 mfma_16x16x32(bfrag8 a, bfrag8 b, floatx4 c) {
    return __builtin_amdgcn_mfma_f32_16x16x32_bf16(a, b, c, 0, 0, 0);
}
__device__ __forceinline__ floatx16 mfma_32x32x16(bfrag8 a, bfrag8 b, floatx16 c) {
    return __builtin_amdgcn_mfma_f32_32x32x16_bf16(a, b, c, 0, 0, 0);
}

// ================= prepass (byte-identical to rounds 5-8 — proven) =================
__global__ __launch_bounds__(256)
void prep_kernel(const float* __restrict__ qp, const float* __restrict__ kp,
                 const float* __restrict__ vp, const int* __restrict__ maskp,
                 unsigned char* __restrict__ ws)
{
    __shared__ __attribute__((aligned(16))) unsigned char parena[64 * 68 * 4];
    const int t = threadIdx.x;
    const int b = blockIdx.x;

    if (b < 1536) {
        int gt  = b * 256 + t;
        int row = gt >> 3;
        int c   = gt & 7;
        const floatx4* qs = (const floatx4*)(qp + row * 64 + c * 8);
        const floatx4* ks = (const floatx4*)(kp + row * 64 + c * 8);
        floatx4 q0 = qs[0], q1 = qs[1];
        floatx4 k0 = ks[0], k1 = ks[1];
        bfrag8 qpk, kpk;
        #pragma unroll
        for (int i = 0; i < 4; ++i) {
            qpk[i] = (__bf16)q0[i]; qpk[4 + i] = (__bf16)q1[i];
            kpk[i] = (__bf16)k0[i]; kpk[4 + i] = (__bf16)k1[i];
        }
        *(bfrag8*)(ws + QB_OFF + row * 128 + c * 16) = qpk;
        *(bfrag8*)(ws + KB_OFF + row * 128 + c * 16) = kpk;
    } else if (b < 2304) {
        int bb = b - 1536, bh = bb >> 5, kt = bb & 31;
        float* lf = (float*)parena;                 // [64 k][68 d]
        const floatx4* vg = (const floatx4*)(vp + (bh * SEQ + kt * 64) * 64);
        #pragma unroll
        for (int it = 0; it < 4; ++it) {
            int f = t + it * 256;
            int r = f >> 4, c4 = f & 15;
            floatx4 val = vg[f];
            #pragma unroll
            for (int i = 0; i < 4; ++i) lf[r * 68 + c4 * 4 + i] = val[i];
        }
        __syncthreads();
        int d = t >> 2, kseg = t & 3;
        unsigned char* tb = ws + VT_OFF + (size_t)(bh * 32 + kt) * 8192 + d * 128;
        #pragma unroll
        for (int jj = 0; jj < 2; ++jj) {
            bfrag8 pk;
            #pragma unroll
            for (int e = 0; e < 8; ++e)
                pk[e] = (__bf16)lf[(kseg * 16 + jj * 8 + e) * 68 + d];
            *(bfrag8*)(tb + (kseg * 2 + jj) * 16) = pk;
        }
    } else {
        int cc = b - 2304, qtb = cc >> 5, kt = cc & 31;
        const int w = t >> 6, lane = t & 63;
        #pragma unroll
        for (int it = 0; it < 16; ++it) {
            int rr = it * 4 + w;
            unsigned long long bl = __ballot(maskp[(qtb * 64 + rr) * SEQ + kt * 64 + lane] != 0);
            if (lane == 0)
                *(unsigned long long*)(ws + MB_OFF + (size_t)((qtb * 32 + kt) * 64 + rr) * 8) = bl;
        }
    }
}

// ======== main (round 9): 32x32x16 MFMA, in-register P via v_permlane32_swap_b32,
//          no sS bridge, 1 barrier/kt, wave = (qh,kh) quadrant of the 64x64 tile ========
__global__ __launch_bounds__(256, 3)
void normattn_main(const unsigned char* __restrict__ ws,
                   const float* __restrict__ gammap, const float* __restrict__ betap,
                   float* __restrict__ outp)
{
    __shared__ __attribute__((aligned(16))) unsigned char sK[2][64 * ROWB];   // slot = tile parity
    __shared__ __attribute__((aligned(16))) unsigned char sV[2][64 * ROWB];

    const int tid  = threadIdx.x;
    const int w    = tid >> 6;
    const int lane = tid & 63;
    const int l32  = lane & 31;
    const int hi   = lane >> 5;
    const int qh   = w & 1;        // q half (32 rows) this wave owns
    const int kh   = w >> 1;       // k half (32 cols of each kt) this wave accumulates
    const int qtb  = blockIdx.x;
    const int bh   = blockIdx.y;
    const int q0   = qtb * 64;

    const unsigned char* gKb = ws + KB_OFF + (size_t)(bh * SEQ) * 128;
    const unsigned char* gVb = ws + VT_OFF + (size_t)(bh * 32) * 8192;
    const unsigned char* gMb = ws + MB_OFF + (size_t)(qtb * 32) * 512;

    // Q fragments (B-operand, 32x32x16): lane holds col q = qh*32+l32, d = dstep*16 + hi*8 + e
    bfrag8 qb[4];
    #pragma unroll
    for (int dstep = 0; dstep < 4; ++dstep)
        qb[dstep] = *(const bfrag8*)(ws + QB_OFF +
                        (size_t)(bh * SEQ + q0 + qh * 32 + l32) * 128 + dstep * 32 + hi * 16);

    // acc[dh]: O^T partial over this wave's k half: d = dh*32 + (r&3)+4*hi+8*(r>>2), q = qh*32+l32
    floatx16 acc[2];
    acc[0] = (floatx16)0.0f;
    acc[1] = (floatx16)0.0f;

    // staging (round-6/8 proven): 512 x 16B chunks per tile, 2 per thread per matrix
    const int sr0 = tid >> 3, sc0 = tid & 7;
    const int sr1 = (tid + 256) >> 3, sc1 = tid & 7;

    auto load_tile = [&](int kt, bfrag8 (&kr)[2], bfrag8 (&vr)[2]) {
        const unsigned char* gK = gKb + (size_t)kt * 8192;
        const unsigned char* gV = gVb + (size_t)kt * 8192;
        kr[0] = *(const bfrag8*)(gK + tid * 16);
        kr[1] = *(const bfrag8*)(gK + (tid + 256) * 16);
        vr[0] = *(const bfrag8*)(gV + tid * 16);
        vr[1] = *(const bfrag8*)(gV + (tid + 256) * 16);
    };
    auto write_tile = [&](int s, bfrag8 (&kr)[2], bfrag8 (&vr)[2]) {
        *(bfrag8*)(&sK[s][0] + sr0 * ROWB + sc0 * 16) = kr[0];
        *(bfrag8*)(&sK[s][0] + sr1 * ROWB + sc1 * 16) = kr[1];
        *(bfrag8*)(&sV[s][0] + sr0 * ROWB + sc0 * 16) = vr[0];
        *(bfrag8*)(&sV[s][0] + sr1 * ROWB + sc1 * 16) = vr[1];
    };

    {   // prologue: stage tiles 0,1
        bfrag8 k0r[2], v0r[2], k1r[2], v1r[2];
        load_tile(0, k0r, v0r);
        load_tile(1, k1r, v1r);
        write_tile(0, k0r, v0r);
        write_tile(1, k1r, v1r);
    }
    asm volatile("s_waitcnt lgkmcnt(0)" ::: "memory");
    asm volatile("s_barrier" ::: "memory");

    // per-wave LDS base addresses
    const unsigned char* kbase = &sK[0][0] + (kh * 32 + l32) * ROWB + hi * 16;
    const unsigned char* vbase = &sV[0][0] + l32 * ROWB + kh * 64 + hi * 16;

    for (int kt = 0; kt < 32; ++kt) {
        const int slot = kt & 1;
        bfrag8 kN[2], vN[2];
        if (kt < 30) load_tile(kt + 2, kN, vN);     // prefetch, vmcnt in flight over compute

        const unsigned long long mrow =
            *(const unsigned long long*)(gMb + (size_t)kt * 512 + (qh * 32 + l32) * 8);

        // ---- QK^T (swapped): S^T[k = kh*32 + kl][q = qh*32 + l32], kl per lane = (r&3)+4hi+8(r>>2)
        floatx16 st = (floatx16)0.0f;
        const unsigned char* cK = kbase + slot * (64 * ROWB);
        #pragma unroll
        for (int dstep = 0; dstep < 4; ++dstep) {
            bfrag8 ka = *(const bfrag8*)(cK + dstep * 32);
            st = mfma_32x32x16(ka, qb[dstep], st);
        }

        // ---- mask + pack to bf16 pairs (u[j] covers kl = {2(j&1)+8(j>>1)} + 4hi, +1)
        const unsigned bits = (unsigned)(mrow >> (kh * 32 + 4 * hi));
        unsigned u[8];
        #pragma unroll
        for (int j = 0; j < 8; ++j) {
            const int kl0 = 2 * (j & 1) + 8 * (j >> 1);
            float a = ((bits >> kl0) & 1u) ? st[2 * j] : -10000.0f;
            float b = ((bits >> (kl0 + 1)) & 1u) ? st[2 * j + 1] : -10000.0f;
            asm("v_cvt_pk_bf16_f32 %0, %1, %2" : "=v"(u[j]) : "v"(a), "v"(b));
        }
        // ---- hi/lo half exchange -> PV B-fragments entirely in registers.
        // After swap(a,b): a = [a.lo | b.lo], b = [a.hi | b.hi].
        asm("v_permlane32_swap_b32 %0, %1" : "+v"(u[0]), "+v"(u[2]));
        asm("v_permlane32_swap_b32 %0, %1" : "+v"(u[1]), "+v"(u[3]));
        asm("v_permlane32_swap_b32 %0, %1" : "+v"(u[4]), "+v"(u[6]));
        asm("v_permlane32_swap_b32 %0, %1" : "+v"(u[5]), "+v"(u[7]));
        union { unsigned int w4[4]; bfrag8 f; } c0, c1;
        c0.w4[0] = u[0]; c0.w4[1] = u[1]; c0.w4[2] = u[2]; c0.w4[3] = u[3];   // kstep 0 (k 0..15 of half)
        c1.w4[0] = u[4]; c1.w4[1] = u[5]; c1.w4[2] = u[6]; c1.w4[3] = u[7];   // kstep 1 (k 16..31)

        // ---- PV: O^T[d][q] += V^T[d][k] * P^T[k][q] over this wave's k half
        const unsigned char* cV = vbase + slot * (64 * ROWB);
        #pragma unroll
        for (int dh = 0; dh < 2; ++dh) {
            bfrag8 va0 = *(const bfrag8*)(cV + dh * 32 * ROWB);
            bfrag8 va1 = *(const bfrag8*)(cV + dh * 32 * ROWB + 32);
            acc[dh] = mfma_32x32x16(va0, c0.f, acc[dh]);
            acc[dh] = mfma_32x32x16(va1, c1.f, acc[dh]);
        }

        asm volatile("s_waitcnt lgkmcnt(0)" ::: "memory");
        asm volatile("s_barrier" ::: "memory");      // all reads of slot done; vmcnt stays in flight
        if (kt < 30) write_tile(slot, kN, vN);       // stage tile kt+2 into freed slot
    }

    // ---- epilogue: sum kh partials cross-wave, then LayerNorm ----
    float* ex = (float*)&sK[0][0];                   // 16 KB exchange area, swizzled chunks
    const int exb = (qh * 64 + lane) * 32;
    if (kh == 1) {
        #pragma unroll
        for (int dh = 0; dh < 2; ++dh)
            #pragma unroll
            for (int jj = 0; jj < 4; ++jj) {
                floatx4 t;
                #pragma unroll
                for (int e = 0; e < 4; ++e) t[e] = acc[dh][jj * 4 + e];
                *(floatx4*)(ex + exb + (((dh * 4 + jj) ^ (lane & 7)) * 4)) = t;
            }
    }
    __syncthreads();
    if (kh == 0) {
        #pragma unroll
        for (int dh = 0; dh < 2; ++dh)
            #pragma unroll
            for (int jj = 0; jj < 4; ++jj) {
                floatx4 t = *(const floatx4*)(ex + exb + (((dh * 4 + jj) ^ (lane & 7)) * 4));
                #pragma unroll
                for (int e = 0; e < 4; ++e) acc[dh][jj * 4 + e] += t[e];
            }
        float s = 0.0f, s2 = 0.0f;
        #pragma unroll
        for (int dh = 0; dh < 2; ++dh)
            #pragma unroll
            for (int r = 0; r < 16; ++r) { float x = acc[dh][r]; s += x; s2 += x * x; }
        s  += __shfl_xor(s, 32);                     // partner lane holds complementary d set
        s2 += __shfl_xor(s2, 32);
        float mean = s * (1.0f / 64.0f);
        float var  = s2 * (1.0f / 64.0f) - mean * mean;
        float rstd = rsqrtf(var + 1e-12f);
        float* orow = outp + (size_t)(bh * SEQ + q0 + qh * 32 + l32) * 64;
        #pragma unroll
        for (int dh = 0; dh < 2; ++dh)
            #pragma unroll
            for (int jj = 0; jj < 4; ++jj) {
                const int d0 = dh * 32 + jj * 8 + 4 * hi;
                floatx4 gg = *(const floatx4*)(gammap + d0);
                floatx4 bb = *(const floatx4*)(betap + d0);
                floatx4 o;
                #pragma unroll
                for (int e = 0; e < 4; ++e)
                    o[e] = (acc[dh][jj * 4 + e] - mean) * rstd * gg[e] + bb[e];
                *(floatx4*)(orow + d0) = o;
            }
    }
}

// ================= fallback (round-2 kernel — proven) =================
#define KROW 72
#define SROW 40
__global__ __launch_bounds__(256, 4)
void normattn_fallback(const float* __restrict__ qp, const float* __restrict__ kp,
                       const float* __restrict__ vp, const int* __restrict__ maskp,
                       const float* __restrict__ gammap, const float* __restrict__ betap,
                       float* __restrict__ outp)
{
    __shared__ __attribute__((aligned(16))) __bf16 sQ[64 * KROW];
    __shared__ __attribute__((aligned(16))) __bf16 sK[64 * KROW];
    __shared__ __attribute__((aligned(16))) __bf16 sV[64 * KROW];
    __shared__ __attribute__((aligned(16))) __bf16 sS[4][16 * SROW];
    __shared__ __attribute__((aligned(8)))  unsigned int sMw[64][2];

    const int tid = threadIdx.x, wave = tid >> 6, lane = tid & 63;
    const int quad = lane >> 4, l16 = lane & 15;
    const int q0 = blockIdx.x * 64, bh = blockIdx.y;
    const int base = bh * SEQ * HD;
    {
        const floatx4* qg = (const floatx4*)(qp + base + q0 * HD);
        #pragma unroll
        for (int it = 0; it < 4; ++it) {
            int idx = tid + it * 256, r = idx >> 4, c = idx & 15;
            floatx4 val = qg[idx];
            bf16x4 pk = {(__bf16)val[0], (__bf16)val[1], (__bf16)val[2], (__bf16)val[3]};
            *(bf16x4*)&sQ[r * KROW + c * 4] = pk;
        }
    }
    __syncthreads();
    bfrag8 qa0 = *(const bfrag8*)&sQ[(wave * 16 + l16) * KROW + quad * 8];
    bfrag8 qa1 = *(const bfrag8*)&sQ[(wave * 16 + l16) * KROW + quad * 8 + 32];
    floatx4 acc[4];
    #pragma unroll
    for (int i = 0; i < 4; ++i) acc[i] = (floatx4)0.0f;
    const int qrow_loc = wave * 16 + quad * 4;
    const int qrb = q0 + qrow_loc;
    for (int kb = 0; kb < SEQ; kb += 64) {
        __syncthreads();
        {
            const floatx4* kg = (const floatx4*)(kp + base + kb * HD);
            #pragma unroll
            for (int it = 0; it < 4; ++it) {
                int idx = tid + it * 256, r = idx >> 4, c = idx & 15;
                floatx4 val = kg[idx];
                bf16x4 pk = {(__bf16)val[0], (__bf16)val[1], (__bf16)val[2], (__bf16)val[3]};
                *(bf16x4*)&sK[r * KROW + c * 4] = pk;
            }
        }
        {
            int d = tid & 63;
            #pragma unroll
            for (int it = 0; it < 4; ++it) {
                int k4 = (tid >> 6) + it * 4;
                bf16x4 pk;
                #pragma unroll
                for (int i = 0; i < 4; ++i) pk[i] = (__bf16)vp[base + (kb + k4 * 4 + i) * HD + d];
                *(bf16x4*)&sV[d * KROW + k4 * 4] = pk;
            }
        }
        #pragma unroll
        for (int it = 0; it < 16; ++it) {
            int rr = it * 4 + wave;
            unsigned long long bl = __ballot(maskp[(q0 + rr) * SEQ + kb + lane] != 0);
            if (lane == 0) { sMw[rr][0] = (unsigned)bl; sMw[rr][1] = (unsigned)(bl >> 32); }
        }
        __syncthreads();
        unsigned long long mrow[4];
        #pragma unroll
        for (int r = 0; r < 4; ++r) mrow[r] = *(const unsigned long long*)&sMw[qrow_loc + r][0];
        #pragma unroll
        for (int kc = 0; kc < 64; kc += 32) {
            floatx4 s0 = (floatx4)0.0f, s1 = (floatx4)0.0f;
            bfrag8 b00 = *(const bfrag8*)&sK[(kc + l16) * KROW + quad * 8];
            bfrag8 b01 = *(const bfrag8*)&sK[(kc + l16) * KROW + quad * 8 + 32];
            bfrag8 b10 = *(const bfrag8*)&sK[(kc + 16 + l16) * KROW + quad * 8];
            bfrag8 b11 = *(const bfrag8*)&sK[(kc + 16 + l16) * KROW + quad * 8 + 32];
            s0 = mfma_16x16x32(qa0, b00, s0);
            s0 = mfma_16x16x32(qa1, b01, s0);
            s1 = mfma_16x16x32(qa0, b10, s1);
            s1 = mfma_16x16x32(qa1, b11, s1);
            #pragma unroll
            for (int r = 0; r < 4; ++r) {
                float v0 = ((mrow[r] >> (kc + l16)) & 1ull) ? s0[r] : -10000.0f;
                float v1 = ((mrow[r] >> (kc + 16 + l16)) & 1ull) ? s1[r] : -10000.0f;
                sS[wave][(quad * 4 + r) * SROW + l16] = (__bf16)v0;
                sS[wave][(quad * 4 + r) * SROW + 16 + l16] = (__bf16)v1;
            }
            asm volatile("s_waitcnt lgkmcnt(0)" ::: "memory");
            bfrag8 pa = *(const bfrag8*)&sS[wave][l16 * SROW + quad * 8];
            #pragma unroll
            for (int nt = 0; nt < 4; ++nt) {
                bfrag8 vb = *(const bfrag8*)&sV[(nt * 16 + l16) * KROW + kc + quad * 8];
                acc[nt] = mfma_16x16x32(pa, vb, acc[nt]);
            }
        }
    }
    float g[4], bt[4];
    #pragma unroll
    for (int nt = 0; nt < 4; ++nt) { g[nt] = gammap[nt * 16 + l16]; bt[nt] = betap[nt * 16 + l16]; }
    #pragma unroll
    for (int r = 0; r < 4; ++r) {
        float s = 0.0f, s2 = 0.0f;
        #pragma unroll
        for (int nt = 0; nt < 4; ++nt) { float xx = acc[nt][r]; s += xx; s2 += xx * xx; }
        #pragma unroll
        for (int off = 1; off < 16; off <<= 1) { s += __shfl_xor(s, off); s2 += __shfl_xor(s2, off); }
        float mean = s * (1.0f / 64.0f);
        float var = s2 * (1.0f / 64.0f) - mean * mean;
        float rstd = rsqrtf(var + 1e-12f);
        float* orow = outp + base + (qrb + r) * HD;
        #pragma unroll
        for (int nt = 0; nt < 4; ++nt)
            orow[nt * 16 + l16] = (acc[nt][r] - mean) * rstd * g[nt] + bt[nt];
    }
}

extern "C" void kernel_launch(void* const* d_in, const int* in_sizes, int n_in,
                              void* d_out, int out_size, void* d_ws, size_t ws_size,
                              hipStream_t stream) {
    const float* q     = (const float*)d_in[0];
    const float* k     = (const float*)d_in[1];
    const float* v     = (const float*)d_in[2];
    const int*   mask  = (const int*)d_in[3];
    const float* gamma = (const float*)d_in[4];
    const float* beta  = (const float*)d_in[5];
    float* out = (float*)d_out;

    dim3 grid(32, NBH);
    if (ws_size >= WS_NEED) {
        unsigned char* ws = (unsigned char*)d_ws;
        prep_kernel<<<3328, 256, 0, stream>>>(q, k, v, mask, ws);
        normattn_main<<<grid, 256, 0, stream>>>(ws, gamma, beta, out);
    } else {
        normattn_fallback<<<grid, 256, 0, stream>>>(q, k, v, mask, gamma, beta, out);
    }
}